// Round 8
// baseline (27.347 us; speedup 1.0000x reference)
//
#include <hip/hip_runtime.h>

#define NB 64
#define NT 512
#define TF 861
#define FPC 7
#define CHUNKS 123            // 123*7 == 861 exactly -> zero bounds checks
#define NSID (NB * CHUNKS)    // 7872 wave-chunks
#define GRID (NSID / 2)       // 3936 blocks of 2 waves; 3936 = 8*492

typedef float v4f __attribute__((ext_vector_type(4)));

// One wave per 7-frame chunk. Wave scans the whole 512-duration row itself
// (8 elems/lane), scatters frame->elem into a private LDS slice from
// registers, then streams 7 frames with a register row-cache + nt stores.
__global__ __launch_bounds__(128, 8) void lr_fused(const float* __restrict__ pred,
                                                   const v4f* __restrict__ batch4,
                                                   v4f* __restrict__ out4) {
    __shared__ int sidx[2][FPC];

    const int bid = blockIdx.x;
    const int sp = (bid & 7) * (GRID >> 3) + (bid >> 3);   // XCD-chunked swizzle
    const int w = threadIdx.x >> 6;
    const int lane = threadIdx.x & 63;
    const int sid = sp * 2 + w;
    const int b = sid / CHUNKS;
    const int chunk = sid - b * CHUNKS;
    const int base = chunk * FPC;

    // ---- per-wave duration scan: lane holds elements [8L, 8L+8) ----
    const v4f* prow = (const v4f*)(pred + b * NT + lane * 8);
    const v4f pa = prow[0];
    const v4f pb = prow[1];
    const int e0 = (int)rintf(fminf(fmaxf(pa.x, 1.f), 10.f));   // round-half-even
    const int e1 = e0 + (int)rintf(fminf(fmaxf(pa.y, 1.f), 10.f));
    const int e2 = e1 + (int)rintf(fminf(fmaxf(pa.z, 1.f), 10.f));
    const int e3 = e2 + (int)rintf(fminf(fmaxf(pa.w, 1.f), 10.f));
    const int e4 = e3 + (int)rintf(fminf(fmaxf(pb.x, 1.f), 10.f));
    const int e5 = e4 + (int)rintf(fminf(fmaxf(pb.y, 1.f), 10.f));
    const int e6 = e5 + (int)rintf(fminf(fmaxf(pb.z, 1.f), 10.f));
    const int e7 = e6 + (int)rintf(fminf(fmaxf(pb.w, 1.f), 10.f));
    int x = e7;
    #pragma unroll
    for (int off = 1; off < 64; off <<= 1) {
        int y = __shfl_up(x, off, 64);
        if (lane >= off) x += y;
    }
    const int excl = x - e7;       // sum of durations in lanes < lane

    if (lane < FPC) sidx[w][lane] = -1;
    __syncthreads();

    // ---- scatter: element g=8*lane+j covers frames [excl+e_{j-1}, excl+e_j) ----
    // frames >= total are covered by no element -> stay -1 -> zeros.
    {
        const int g8 = lane * 8;
        const int wend = base + FPC;
        int st = excl;
#define SCAT(J, EJ) { const int en = excl + (EJ);                        \
        int lo = st > base ? st : base;                                  \
        const int hi = en < wend ? en : wend;                            \
        for (; lo < hi; ++lo) sidx[w][lo - base] = g8 + (J);             \
        st = en; }
        SCAT(0, e0) SCAT(1, e1) SCAT(2, e2) SCAT(3, e3)
        SCAT(4, e4) SCAT(5, e5) SCAT(6, e6) SCAT(7, e7)
#undef SCAT
    }
    __syncthreads();

    // ---- stream 7 frames: register row-cache, nt stores ----
    const int i0 = sidx[w][0], i1 = sidx[w][1], i2 = sidx[w][2],
              i3 = sidx[w][3], i4 = sidx[w][4], i5 = sidx[w][5],
              i6 = sidx[w][6];
    const v4f* srcb = batch4 + ((size_t)b << 16);             // b*512*128
    v4f* dstb = out4 + (((size_t)b * TF + base) << 7);
    int cur = -2;
    v4f v0 = (v4f)0.f, v1 = (v4f)0.f;
#define STEP(K, IK)                                                      \
    {                                                                    \
        if ((IK) != cur) {                                               \
            cur = (IK);                                                  \
            if ((IK) >= 0) {                                             \
                const v4f* s = srcb + ((size_t)(IK) << 7);               \
                v0 = s[lane]; v1 = s[lane + 64];                         \
            } else { v0 = (v4f)0.f; v1 = (v4f)0.f; }                     \
        }                                                                \
        v4f* d = dstb + ((size_t)(K) << 7);                              \
        __builtin_nontemporal_store(v0, d + lane);                       \
        __builtin_nontemporal_store(v1, d + lane + 64);                  \
    }
    STEP(0, i0) STEP(1, i1) STEP(2, i2) STEP(3, i3)
    STEP(4, i4) STEP(5, i5) STEP(6, i6)
#undef STEP
}

extern "C" void kernel_launch(void* const* d_in, const int* in_sizes, int n_in,
                              void* d_out, int out_size, void* d_ws, size_t ws_size,
                              hipStream_t stream) {
    const float* batch = (const float*)d_in[0];
    const float* pred  = (const float*)d_in[1];
    float* out = (float*)d_out;

    lr_fused<<<GRID, 128, 0, stream>>>(pred, (const v4f*)batch, (v4f*)out);
}